// Round 9
// baseline (643.704 us; speedup 1.0000x reference)
//
#include <hip/hip_runtime.h>
#include <math.h>

#define BOX 128
#define MCELLS (BOX*BOX*BOX)
#define TABN 512
#define SATN 256
typedef unsigned short u16;

__device__ __forceinline__ float bf2f(u16 h) {
  union { unsigned u; float f; } c; c.u = ((unsigned)h) << 16; return c.f;
}
__device__ __forceinline__ u16 f2bf(float f) {
  union { float f; unsigned u; } c; c.f = f;
  unsigned r = c.u + 0x7FFF + ((c.u >> 16) & 1);   // RNE
  return (u16)(r >> 16);
}
__device__ __forceinline__ unsigned pk2(float a, float b) {
  return (unsigned)f2bf(a) | ((unsigned)f2bf(b) << 16);
}
__device__ __forceinline__ float plo(unsigned p) {
  union { unsigned u; float f; } c; c.u = p << 16; return c.f;
}
__device__ __forceinline__ float phh(unsigned p) {
  union { unsigned u; float f; } c; c.u = p & 0xFFFF0000u; return c.f;
}
__device__ __forceinline__ void up8(uint4 p, float* o) {
  o[0] = plo(p.x); o[1] = phh(p.x); o[2] = plo(p.y); o[3] = phh(p.y);
  o[4] = plo(p.z); o[5] = phh(p.z); o[6] = plo(p.w); o[7] = phh(p.w);
}
__device__ __forceinline__ uint4 pk8(const float* o) {
  return make_uint4(pk2(o[0], o[1]), pk2(o[2], o[3]),
                    pk2(o[4], o[5]), pk2(o[6], o[7]));
}

// f(u) = log(clip(0.5*(1+erf(u)))) — table builder only
__device__ __forceinline__ float f_exact(float u) {
  float au = fabsf(u);
  float tt = __builtin_amdgcn_rcpf(fmaf(0.3275911f, au, 1.0f));
  float poly = tt * fmaf(tt, fmaf(tt, fmaf(tt, fmaf(tt, 1.061405429f,
                   -1.453152027f), 1.421413741f), -0.284496736f),
                   0.254829592f);
  float e = fmaf(-poly, __expf(-u * u), 1.0f);
  float erfu = (u < 0.0f) ? -e : e;
  float s = fmaf(0.5f, erfu, 0.5f);
  s = fminf(fmaxf(s, 1e-6f), 1.0f);
  return __logf(s);
}

// table over u in [-1.8, 2.2); last bin EXACTLY zero (bulk invariant).
__device__ __forceinline__ float tlook(const float2* __restrict__ ftab,
                                       float r2, float aoff, float hidu) {
  float r = sqrtf(r2 + 1e-12f);
  float t = fmaf(r, hidu, aoff);
  t = fminf(fmaxf(t, 0.0f), 511.75f);
  int j = (int)t;
  float fr = t - (float)j;
  float2 e = ftab[j];
  return fmaf(fr, e.y, e.x);
}

// ---------------------------------------------------------------------------
// Stage A (gather): one block per 8x8x32 tile (4x fewer blocks -> 4x less
// atom-list re-read traffic). 8 z-cells/thread. Writes fp32 eps (output)
// plus bf16 ex/ey/ez packs for the Jacobi. Empty tiles early-out.
// ---------------------------------------------------------------------------
__global__ __launch_bounds__(256) void eps_gather_kernel(
    const float* __restrict__ coords, const float* __restrict__ params,
    const int* __restrict__ num_atoms, float* __restrict__ eps_out,
    u16* __restrict__ exb, u16* __restrict__ eyb, u16* __restrict__ ezb,
    int N) {
  __shared__ float4 sat[SATN];
  __shared__ float2 ftab[TABN];
  __shared__ int scnt;

  const int xt = blockIdx.x, yt = blockIdx.y;
  const int bz = blockIdx.z;
  const int b = bz >> 2, zt = bz & 3;
  const int tid = threadIdx.x;

  const float u0 = -1.8f;
  const float du = (2.2f - u0) / (float)TABN;
  const float inv_du = (float)TABN / (2.2f - u0);
  const float hidu = 0.5f * inv_du;

  if (tid == 0) scnt = 0;
  __syncthreads();

  const float lox = (float)(xt * 8),  hix = lox + 7.5f;
  const float loy = (float)(yt * 8),  hiy = loy + 7.5f;
  const float loz = (float)(zt * 32), hiz = loz + 31.5f;

  const int na = num_atoms[b];
  for (int a = tid; a < N; a += 256) {
    if (a < na) {
      float ax = coords[(size_t)b * 3 * N + a * 3 + 0];
      float ay = coords[(size_t)b * 3 * N + a * 3 + 1];
      float az = coords[(size_t)b * 3 * N + a * 3 + 2];
      float rad = params[((size_t)b * N + a) * 2 + 1];
      float cx = fminf(fmaxf(ax, lox), hix);
      float cy = fminf(fmaxf(ay, loy), hiy);
      float cz = fminf(fmaxf(az, loz), hiz);
      float ddx = ax - cx, ddy = ay - cy, ddz = az - cz;
      float cut = rad + 5.85f;            // Rw + 4.4 (u<2.2) + slack
      if (ddx * ddx + ddy * ddy + ddz * ddz < cut * cut) {
        int s = atomicAdd(&scnt, 1);
        if (s < SATN) sat[s] = make_float4(ax, ay, az, rad);
      }
    }
  }
  __syncthreads();
  const int cnt = min(scnt, SATN);

  // thread -> (xx, yy, zq); 8 consecutive z-cells per thread
  const int zq = tid & 3, yy = (tid >> 2) & 7, xx = tid >> 5;
  const int xi = xt * 8 + xx, yi = yt * 8 + yy, zi = zt * 32 + zq * 8;
  const int v = (xi << 14) + (yi << 7) + zi;
  const size_t eb = (size_t)b * 4 * MCELLS;
  const size_t cb = (size_t)b * MCELLS + v;

  if (cnt == 0) {
    float c79[8] = {79, 79, 79, 79, 79, 79, 79, 79};
    float c0[8]  = {0, 0, 0, 0, 0, 0, 0, 0};
#pragma unroll
    for (int ch = 0; ch < 3; ++ch) {
      *(float4*)(eps_out + eb + (size_t)ch * MCELLS + v)     =
          make_float4(79, 79, 79, 79);
      *(float4*)(eps_out + eb + (size_t)ch * MCELLS + v + 4) =
          make_float4(79, 79, 79, 79);
    }
    *(float4*)(eps_out + eb + (size_t)3 * MCELLS + v)     = make_float4(0,0,0,0);
    *(float4*)(eps_out + eb + (size_t)3 * MCELLS + v + 4) = make_float4(0,0,0,0);
    *(uint4*)(exb + cb) = pk8(c79);
    *(uint4*)(eyb + cb) = pk8(c79);
    *(uint4*)(ezb + cb) = pk8(c79);
    (void)c0;
    return;
  }

  for (int j = tid; j < TABN; j += 256) {
    float uj = fmaf(du, (float)j, u0);
    float f0 = f_exact(uj);
    float f1 = f_exact(uj + du);
    ftab[j] = (j == TABN - 1) ? make_float2(0.0f, 0.0f)
                              : make_float2(f0, f1 - f0);
  }
  __syncthreads();

  const float xf = (float)xi, yf = (float)yi, zf = (float)zi;
  float acc[4][8];
#pragma unroll
  for (int ch = 0; ch < 4; ++ch)
#pragma unroll
    for (int k = 0; k < 8; ++k) acc[ch][k] = 0.0f;

  for (int j = 0; j < cnt; ++j) {
    float4 A = sat[j];
    float dx = xf - A.x, dy = yf - A.y, dzb = zf - A.z;
    float Rw = A.w + 1.4f;
    float cw = Rw + 4.4f;
    float cw2 = cw * cw;
    float aW = (1.8f - 0.5f * Rw) * inv_du;
    float aI = aW + 0.2f * inv_du;

    float dx2 = dx * dx, dxh = dx + 0.5f, dxh2 = dxh * dxh;
    float dy2 = dy * dy, dyh = dy + 0.5f, dyh2 = dyh * dyh;
    float mdx = fminf(dx2, dxh2);
    float mdy = fminf(dy2, dyh2);
    float zhi = dzb + 7.5f;               // strip spans [dzb, dzb+7.5]
    float mdz = (dzb > 0.f) ? dzb * dzb : (zhi < 0.f ? zhi * zhi : 0.f);
    if (mdx + mdy + mdz >= cw2) continue;

#pragma unroll
    for (int k = 0; k < 8; ++k) {
      float dzv = dzb + (float)k;
      float dz2 = dzv * dzv, dzh = dzv + 0.5f, dzh2 = dzh * dzh;
      acc[0][k] += tlook(ftab, dxh2 + dy2 + dz2, aW, hidu);
      acc[1][k] += tlook(ftab, dx2 + dyh2 + dz2, aW, hidu);
      acc[2][k] += tlook(ftab, dx2 + dy2 + dzh2, aW, hidu);
      acc[3][k] += tlook(ftab, dx2 + dy2 + dz2, aI, hidu);
    }
  }

  float ev[4][8];
#pragma unroll
  for (int ch = 0; ch < 4; ++ch) {
#pragma unroll
    for (int k = 0; k < 8; ++k) {
      float e = __expf(acc[ch][k]);
      ev[ch][k] = (ch < 3) ? fmaf(72.5f, e, 6.5f) : (1.0f - e);
    }
    *(float4*)(eps_out + eb + (size_t)ch * MCELLS + v) =
        make_float4(ev[ch][0], ev[ch][1], ev[ch][2], ev[ch][3]);
    *(float4*)(eps_out + eb + (size_t)ch * MCELLS + v + 4) =
        make_float4(ev[ch][4], ev[ch][5], ev[ch][6], ev[ch][7]);
  }
  *(uint4*)(exb + cb) = pk8(ev[0]);
  *(uint4*)(eyb + cb) = pk8(ev[1]);
  *(uint4*)(ezb + cb) = pk8(ev[2]);
}

// ---------------------------------------------------------------------------
// Stage B: trilinear charge scatter (CHARGE_CONV folded in).
// ---------------------------------------------------------------------------
__global__ __launch_bounds__(256) void q_scatter_kernel(
    const float* __restrict__ coords, const float* __restrict__ params,
    const int* __restrict__ num_atoms, float* __restrict__ q, int N, int B) {
  int t = blockIdx.x * blockDim.x + threadIdx.x;
  if (t >= B * N) return;
  int b = t / N, atom = t % N;
  if (atom >= num_atoms[b]) return;

  const float x = coords[(size_t)b * 3 * N + atom * 3 + 0];
  const float y = coords[(size_t)b * 3 * N + atom * 3 + 1];
  const float z = coords[(size_t)b * 3 * N + atom * 3 + 2];
  const float c = params[((size_t)b * N + atom) * 2 + 0] * 7046.52f;

  float fx0 = floorf(x), fy0 = floorf(y), fz0 = floorf(z);
  int ix = (int)fx0, iy = (int)fy0, iz = (int)fz0;
  float fx = x - fx0, fy = y - fy0, fz = z - fz0;

  float* __restrict__ g = q + (size_t)b * MCELLS;
  for (int k = 0; k < 8; ++k) {
    int cx = (k >> 2) & 1, cy = (k >> 1) & 1, cz = k & 1;
    int jx = ix + cx, jy = iy + cy, jz = iz + cz;
    if ((unsigned)jx >= (unsigned)BOX || (unsigned)jy >= (unsigned)BOX ||
        (unsigned)jz >= (unsigned)BOX) continue;
    float w = (cx ? fx : 1.0f - fx) * (cy ? fy : 1.0f - fy) *
              (cz ? fz : 1.0f - fz);
    atomicAdd(&g[(jx * BOX + jy) * BOX + jz], w * c);
  }
}

// ---------------------------------------------------------------------------
// Prep (8 cells/thread): reads bf16 ex/ey/ez (what the sweeps consume) +
// fp32 lm/q; writes rdn, rq2, phiA (=rq), purity bytes. Purity is judged on
// the bf16 values -> exactly consistent with the sweep's bulk constants.
// ---------------------------------------------------------------------------
__global__ __launch_bounds__(256) void prep8_kernel(
    const float* __restrict__ eps, const float* __restrict__ q,
    const u16* __restrict__ exb, const u16* __restrict__ eyb,
    const u16* __restrict__ ezb,
    u16* __restrict__ rdn, u16* __restrict__ rq2, u16* __restrict__ phiA,
    unsigned char* __restrict__ pure, int B) {
  const int per_b = MCELLS / 8;   // 2^18
  int t = blockIdx.x * 256 + threadIdx.x;
  if (t >= B * per_b) return;
  int b = t >> 18;
  int r = t & (per_b - 1);
  int zg = r & 15, y = (r >> 4) & 127, x = r >> 11;
  int z0 = zg << 3;
  int v = (x << 14) | (y << 7) | z0;
  size_t cell = (size_t)b * MCELLS + v;

  const float* lm = eps + (size_t)(b * 4 + 3) * MCELLS;
  const uint4 z4 = make_uint4(0, 0, 0, 0);

  uint4 ec = *(const uint4*)(exb + cell);
  uint4 yc = *(const uint4*)(eyb + cell);
  uint4 zc = *(const uint4*)(ezb + cell);
  uint4 em = (x > 0) ? *(const uint4*)(exb + cell - 16384) : z4;
  uint4 ym = (y > 0) ? *(const uint4*)(eyb + cell - 128) : z4;
  u16 ezm0 = (z0 > 0) ? ezb[cell - 1] : (u16)0;

  float exA[8], eyA[8], xmA[8], ymA[8], ezA9[9], lA[8], qA[8];
  up8(ec, exA); up8(yc, eyA); up8(em, xmA); up8(ym, ymA);
  ezA9[0] = bf2f(ezm0); up8(zc, ezA9 + 1);
  *(float4*)(lA)     = *(const float4*)(lm + v);
  *(float4*)(lA + 4) = *(const float4*)(lm + v + 4);
  *(float4*)(qA)     = *(const float4*)(q + cell);
  *(float4*)(qA + 4) = *(const float4*)(q + cell + 4);

  float rdA[8], rqA[8];
  bool pu = true;
#pragma unroll
  for (int i = 0; i < 8; ++i) {
    float den = exA[i] + xmA[i] + eyA[i] + ymA[i] + ezA9[i + 1] + ezA9[i] +
                0.106f * lA[i];
    rdA[i] = __builtin_amdgcn_rcpf(den);
    rqA[i] = qA[i] * rdA[i];
    pu &= (exA[i] == 79.0f) & (eyA[i] == 79.0f) & (ezA9[i + 1] == 79.0f) &
          (lA[i] == 0.0f) & (qA[i] == 0.0f);
  }
  *(uint4*)(rdn + cell) = pk8(rdA);
  uint4 rqp = pk8(rqA);
  *(uint4*)(rq2 + cell) = rqp;
  *(uint4*)(phiA + cell) = rqp;   // phi after sweep 1 (phi0 = 0)

  unsigned long long bal = __ballot(pu);
  int lane = threadIdx.x & 63;
  if ((lane & 15) == 0) {
    unsigned m = (unsigned)((bal >> (lane & 48)) & 0xFFFFull);
    pure[((size_t)b << 14) + (x << 7) + y] = (m == 0xFFFFu) ? 1 : 0;
  }
}

// bulk flag per (x, y-quad) for the single final sweep
__global__ __launch_bounds__(256) void flag_kernel(
    const unsigned char* __restrict__ pure, unsigned char* __restrict__ flags,
    int B) {
  int t = blockIdx.x * 256 + threadIdx.x;
  if (t >= B * 128 * 32) return;
  int b = t >> 12;
  int r = t & 4095;
  int x = r >> 5, yq = r & 31;
  unsigned char f = 0;
  if (x > 0 && x < 127 && yq > 0 && yq < 31) {
    const unsigned char* P = pure + ((size_t)b << 14);
    bool ok = true;
    int y0 = yq << 2;
    for (int dx = -1; dx <= 1; ++dx)
      for (int yy = y0 - 1; yy <= y0 + 4; ++yy)
        ok &= (P[(x + dx) * 128 + yy] != 0);
    f = ok ? 1 : 0;
  }
  flags[t] = f;
}

// ---------------------------------------------------------------------------
// 8-z-cell stencil step reading phi from an LDS tile.
// ---------------------------------------------------------------------------
__device__ __forceinline__ void stage8(
    const u16* __restrict__ sp, int cst, int c0, int z0, size_t cell,
    int gx, int gy, bool bulk,
    const u16* __restrict__ exb, const u16* __restrict__ eyb,
    const u16* __restrict__ ezb, const u16* __restrict__ rdn,
    const u16* __restrict__ rq2, float* o) {
  const u16* pc0 = sp + (c0 << 7) + z0;
  uint4 pc = *(const uint4*)pc0;
  u16 zmu = (z0 > 0)   ? pc0[-1] : (u16)0;
  u16 zpu = (z0 < 120) ? pc0[8]  : (u16)0;
  uint4 xp = *(const uint4*)(pc0 + (cst << 7));
  uint4 xm = *(const uint4*)(pc0 - (cst << 7));
  uint4 yp = *(const uint4*)(pc0 + 128);
  uint4 ym = *(const uint4*)(pc0 - 128);

  float pz[10];
  pz[0] = bf2f(zmu); up8(pc, pz + 1); pz[9] = bf2f(zpu);
  float xpA[8], xmA[8], ypA[8], ymA[8];
  up8(xp, xpA); up8(xm, xmA); up8(yp, ypA); up8(ym, ymA);

  if (bulk) {
    float rdc  = bf2f(f2bf(__builtin_amdgcn_rcpf(474.0f)));   // 6*79
    float rdc0 = bf2f(f2bf(__builtin_amdgcn_rcpf(395.0f)));   // z=0
#pragma unroll
    for (int i = 0; i < 8; ++i) {
      float s = xpA[i] + xmA[i] + ypA[i] + ymA[i] + pz[i] + pz[i + 2];
      float rd = (z0 + i == 0) ? rdc0 : rdc;
      o[i] = rd * (79.0f * s);
    }
  } else {
    const uint4 z4 = make_uint4(0, 0, 0, 0);
    uint4 ec  = *(const uint4*)(exb + cell);
    uint4 em  = (gx > 0) ? *(const uint4*)(exb + cell - 16384) : z4;
    uint4 yc  = *(const uint4*)(eyb + cell);
    uint4 ym4 = (gy > 0) ? *(const uint4*)(eyb + cell - 128) : z4;
    uint4 zc  = *(const uint4*)(ezb + cell);
    u16 ezm0  = (z0 > 0) ? ezb[cell - 1] : (u16)0;
    uint4 rd4 = *(const uint4*)(rdn + cell);
    uint4 rq4 = *(const uint4*)(rq2 + cell);
    float exA[8], exmA[8], eyA[8], eymA[8], ezA[9], rdA[8], rqA[8];
    up8(ec, exA); up8(em, exmA); up8(yc, eyA); up8(ym4, eymA);
    ezA[0] = bf2f(ezm0); up8(zc, ezA + 1);
    up8(rd4, rdA); up8(rq4, rqA);
#pragma unroll
    for (int i = 0; i < 8; ++i) {
      float num = exA[i] * xpA[i];
      num = fmaf(exmA[i], xmA[i], num);
      num = fmaf(eyA[i],  ypA[i], num);
      num = fmaf(eymA[i], ymA[i], num);
      num = fmaf(ezA[i + 1], pz[i + 2], num);
      num = fmaf(ezA[i],     pz[i],     num);
      o[i] = fmaf(rdA[i], num, rqA[i]);
    }
  }
}

// ---------------------------------------------------------------------------
// Fused double sweep with XCD-aware block swizzle: flat%8 selects XCD
// (dispatch round-robin heuristic); each XCD owns a fixed 16-cell x-slab so
// its coefficient slab (~5 MB) stays hot in its private L2 across all 14
// dispatches. Correctness independent of the actual mapping.
// ---------------------------------------------------------------------------
__global__ __launch_bounds__(256) void fused2_kernel(
    const u16* __restrict__ pin, u16* __restrict__ pout,
    const u16* __restrict__ exb, const u16* __restrict__ eyb,
    const u16* __restrict__ ezb, const u16* __restrict__ rdn,
    const u16* __restrict__ rq2, const unsigned char* __restrict__ pure) {
  __shared__ u16 s0[12 * 12 * 128];
  __shared__ u16 s1[10 * 10 * 128];
  __shared__ unsigned char sbulk[144];

  const int flat = blockIdx.x;
  const int xcd = flat & 7;
  const int idx = flat >> 3;
  const int x0 = (((xcd << 1) | (idx & 1))) * 8;
  const int rem = idx >> 1;
  const int y0 = (rem & 15) * 8;
  const int b = rem >> 4;

  const int tid = threadIdx.x;
  const size_t bbase = (size_t)b << 21;
  const uint4 z4 = make_uint4(0, 0, 0, 0);

  if (tid < 144) {
    int cx = tid / 12, cy = tid - (tid / 12) * 12;
    int gx = x0 - 2 + cx, gy = y0 - 2 + cy;
    bool ok = false;
    if (gx >= 1 && gx <= 126 && gy >= 1 && gy <= 126) {
      const unsigned char* P = pure + ((size_t)b << 14);
      ok = P[(gx << 7) + gy] && P[((gx - 1) << 7) + gy] &&
           P[((gx + 1) << 7) + gy] && P[(gx << 7) + gy - 1] &&
           P[(gx << 7) + gy + 1];
    }
    sbulk[tid] = ok ? 1 : 0;
  }

  for (int i = tid; i < 144 * 16; i += 256) {
    int col = i >> 4, zc = i & 15;
    int cx = col / 12, cy = col - (col / 12) * 12;
    int gx = x0 - 2 + cx, gy = y0 - 2 + cy;
    uint4 vv = z4;
    if ((unsigned)gx < 128u && (unsigned)gy < 128u)
      vv = *(const uint4*)(pin + (bbase | (gx << 14) | (gy << 7) | (zc << 3)));
    ((uint4*)s0)[(col << 4) + zc] = vv;
  }
  __syncthreads();

  for (int u = tid; u < 100 * 16; u += 256) {
    int col = u >> 4, zc = u & 15, zz = zc << 3;
    int cx = col / 10, cy = col - (col / 10) * 10;
    int gx = x0 - 1 + cx, gy = y0 - 1 + cy;
    uint4* dst = (uint4*)(s1 + (col << 7) + zz);
    if ((unsigned)gx >= 128u || (unsigned)gy >= 128u) { *dst = z4; continue; }
    int c0 = (cx + 1) * 12 + (cy + 1);
    size_t cell = bbase | (gx << 14) | (gy << 7) | zz;
    float o[8];
    stage8(s0, 12, c0, zz, cell, gx, gy, sbulk[c0] != 0,
           exb, eyb, ezb, rdn, rq2, o);
    *dst = pk8(o);
  }
  __syncthreads();

  for (int u = tid; u < 64 * 16; u += 256) {
    int col = u >> 4, zc = u & 15, zz = zc << 3;
    int cx = col >> 3, cy = col & 7;
    int gx = x0 + cx, gy = y0 + cy;
    int c1 = (cx + 1) * 10 + (cy + 1);
    size_t cell = bbase | (gx << 14) | (gy << 7) | zz;
    float o[8];
    stage8(s1, 10, c1, zz, cell, gx, gy,
           sbulk[(cx + 2) * 12 + (cy + 2)] != 0, exb, eyb, ezb, rdn, rq2, o);
    *(uint4*)(pout + cell) = pk8(o);
  }
}

// ---------------------------------------------------------------------------
// Single sweep (final): fp32 write to d_out.
// ---------------------------------------------------------------------------
__global__ __launch_bounds__(256) void sweep_final_kernel(
    const u16* __restrict__ pin, float* __restrict__ poutf,
    const u16* __restrict__ exb, const u16* __restrict__ eyb,
    const u16* __restrict__ ezb, const u16* __restrict__ rdn,
    const u16* __restrict__ rq2, const unsigned char* __restrict__ flags,
    int units) {
  int t = blockIdx.x * 256 + threadIdx.x;
  if (t >= units) return;
  int b = t >> 18;
  int r = t & ((1 << 18) - 1);
  int zg = r & 15, y = (r >> 4) & 127, x = r >> 11;
  int z0 = zg << 3;
  int v = (x << 14) | (y << 7) | z0;
  size_t cell = (size_t)b * MCELLS + v;

  const uint4 z4 = make_uint4(0, 0, 0, 0);
  uint4 pc = *(const uint4*)(pin + cell);
  u16 zmu = (z0 > 0)   ? pin[cell - 1] : (u16)0;
  u16 zpu = (z0 < 120) ? pin[cell + 8] : (u16)0;
  uint4 xp = (x < 127) ? *(const uint4*)(pin + cell + 16384) : z4;
  uint4 xm = (x > 0)   ? *(const uint4*)(pin + cell - 16384) : z4;
  uint4 yp = (y < 127) ? *(const uint4*)(pin + cell + 128) : z4;
  uint4 ym = (y > 0)   ? *(const uint4*)(pin + cell - 128) : z4;

  float pz[10];
  pz[0] = bf2f(zmu); up8(pc, pz + 1); pz[9] = bf2f(zpu);
  float xpA[8], xmA[8], ypA[8], ymA[8];
  up8(xp, xpA); up8(xm, xmA); up8(yp, ypA); up8(ym, ymA);

  bool bulk = flags[(b << 12) + (x << 5) + (y >> 2)] != 0;

  float o[8];
  if (bulk) {
    float rdc  = bf2f(f2bf(__builtin_amdgcn_rcpf(474.0f)));
    float rdc0 = bf2f(f2bf(__builtin_amdgcn_rcpf(395.0f)));
#pragma unroll
    for (int i = 0; i < 8; ++i) {
      float s = xpA[i] + xmA[i] + ypA[i] + ymA[i] + pz[i] + pz[i + 2];
      float rd = (z0 + i == 0) ? rdc0 : rdc;
      o[i] = rd * (79.0f * s);
    }
  } else {
    uint4 ec  = *(const uint4*)(exb + cell);
    uint4 em  = (x > 0) ? *(const uint4*)(exb + cell - 16384) : z4;
    uint4 yc  = *(const uint4*)(eyb + cell);
    uint4 ym4 = (y > 0) ? *(const uint4*)(eyb + cell - 128) : z4;
    uint4 zc  = *(const uint4*)(ezb + cell);
    u16 ezm0  = (z0 > 0) ? ezb[cell - 1] : (u16)0;
    uint4 rd4 = *(const uint4*)(rdn + cell);
    uint4 rq4 = *(const uint4*)(rq2 + cell);
    float exA[8], exmA[8], eyA[8], eymA[8], ezA[9], rdA[8], rqA[8];
    up8(ec, exA); up8(em, exmA); up8(yc, eyA); up8(ym4, eymA);
    ezA[0] = bf2f(ezm0); up8(zc, ezA + 1);
    up8(rd4, rdA); up8(rq4, rqA);
#pragma unroll
    for (int i = 0; i < 8; ++i) {
      float num = exA[i] * xpA[i];
      num = fmaf(exmA[i], xmA[i], num);
      num = fmaf(eyA[i],  ypA[i], num);
      num = fmaf(eymA[i], ymA[i], num);
      num = fmaf(ezA[i + 1], pz[i + 2], num);
      num = fmaf(ezA[i],     pz[i],     num);
      o[i] = fmaf(rdA[i], num, rqA[i]);
    }
  }
  *(float4*)(poutf + cell)     = make_float4(o[0], o[1], o[2], o[3]);
  *(float4*)(poutf + cell + 4) = make_float4(o[4], o[5], o[6], o[7]);
}

// ---------------------------------------------------------------------------
// Fallback fp32 Jacobi (tiny ws)
// ---------------------------------------------------------------------------
__global__ __launch_bounds__(256) void jacobi_kernel(
    const float* __restrict__ phi_in, float* __restrict__ phi_out,
    const float* __restrict__ eps, const float* __restrict__ rhs, int B) {
  int i = blockIdx.x * blockDim.x + threadIdx.x;
  if (i >= B * MCELLS) return;
  int b = i >> 21;
  int v = i & (MCELLS - 1);
  int z = v & 127, y = (v >> 7) & 127, x = v >> 14;

  const float* ex = eps + (size_t)(b * 4 + 0) * MCELLS;
  const float* ey = eps + (size_t)(b * 4 + 1) * MCELLS;
  const float* ez = eps + (size_t)(b * 4 + 2) * MCELLS;
  const float* lm = eps + (size_t)(b * 4 + 3) * MCELLS;
  const float* p  = phi_in + (size_t)b * MCELLS;

  float exc = ex[v], eyc = ey[v], ezc = ez[v];
  float exm = (x > 0) ? ex[v - BOX * BOX] : 0.0f;
  float eym = (y > 0) ? ey[v - BOX]       : 0.0f;
  float ezm = (z > 0) ? ez[v - 1]         : 0.0f;

  float num = rhs[i];
  num += (x < BOX - 1) ? exc * p[v + BOX * BOX] : 0.0f;
  num += (x > 0)       ? exm * p[v - BOX * BOX] : 0.0f;
  num += (y < BOX - 1) ? eyc * p[v + BOX]       : 0.0f;
  num += (y > 0)       ? eym * p[v - BOX]       : 0.0f;
  num += (z < BOX - 1) ? ezc * p[v + 1]         : 0.0f;
  num += (z > 0)       ? ezm * p[v - 1]         : 0.0f;

  float den = exc + exm + eyc + eym + ezc + ezm + 0.106f * lm[v];
  phi_out[i] = num / den;
}

// ---------------------------------------------------------------------------
extern "C" void kernel_launch(void* const* d_in, const int* in_sizes, int n_in,
                              void* d_out, int out_size, void* d_ws,
                              size_t ws_size, hipStream_t stream) {
  const float* coords    = (const float*)d_in[0];
  const float* params    = (const float*)d_in[1];
  const int*   num_atoms = (const int*)d_in[2];

  const int B = in_sizes[2];
  const int N = in_sizes[1] / (2 * B);

  float* out = (float*)d_out;
  float* q   = out;                            // (B, M)
  float* eps = out + (size_t)B * MCELLS;       // (B, 4, M)
  float* phi = out + (size_t)B * MCELLS * 5;   // (B, M)

  const size_t BM = (size_t)B * MCELLS;
  u16* phiA = (u16*)d_ws;
  u16* phiB = phiA + BM;
  u16* exb  = phiB + BM;
  u16* eyb  = exb + BM;
  u16* ezb  = eyb + BM;
  u16* rdn  = ezb + BM;
  u16* rq2  = rdn + BM;
  unsigned char* pureb = (unsigned char*)(rq2 + BM);
  unsigned char* flags = pureb + (size_t)B * 16384;
  const size_t need = BM * 14 + (size_t)B * (16384 + 4096);

  const bool fast = (ws_size >= need);

  hipMemsetAsync(q, 0, sizeof(float) * BM, stream);   // scatter accumulator

  eps_gather_kernel<<<dim3(16, 16, 4 * B), 256, 0, stream>>>(
      coords, params, num_atoms, eps,
      fast ? exb : (u16*)d_ws, fast ? eyb : (u16*)d_ws,
      fast ? ezb : (u16*)d_ws, N);
  q_scatter_kernel<<<(B * N + 255) / 256, 256, 0, stream>>>(
      coords, params, num_atoms, q, N, B);

  if (fast) {
    const int pblocks = B * 1024;
    prep8_kernel<<<pblocks, 256, 0, stream>>>(eps, q, exb, eyb, ezb, rdn, rq2,
                                              phiA, pureb, B);
    flag_kernel<<<(B * 4096 + 255) / 256, 256, 0, stream>>>(pureb, flags, B);

    // prep did sweep 1 (phi1 in phiA). 14 fused pairs = sweeps 2..29,
    // ping-pong A->B->A (phi29 ends in A). Final single sweep 30 -> fp32 out.
    u16* pa = phiA;
    u16* pb = phiB;
    for (int k = 0; k < 14; ++k) {
      fused2_kernel<<<256 * B, 256, 0, stream>>>(
          pa, pb, exb, eyb, ezb, rdn, rq2, pureb);
      u16* tmp = pa; pa = pb; pb = tmp;
    }
    const int units = B * (MCELLS / 8);
    sweep_final_kernel<<<(units + 255) / 256, 256, 0, stream>>>(
        pa, phi, exb, eyb, ezb, rdn, rq2, flags, units);
  } else {
    hipMemsetAsync(phi, 0, sizeof(float) * BM, stream);
    float* pa = phi;
    float* pb = (float*)d_ws;
    int total = (int)BM;
    for (int it = 0; it < 30; ++it) {
      jacobi_kernel<<<(total + 255) / 256, 256, 0, stream>>>(pa, pb, eps, q, B);
      float* tmp = pa; pa = pb; pb = tmp;
    }
  }
}

// Round 10
// 553.936 us; speedup vs baseline: 1.1621x; 1.1621x over previous
//
#include <hip/hip_runtime.h>
#include <math.h>

#define BOX 128
#define MCELLS (BOX*BOX*BOX)
#define TABN 512
#define SATN 256
typedef unsigned short u16;

__device__ __forceinline__ float bf2f(u16 h) {
  union { unsigned u; float f; } c; c.u = ((unsigned)h) << 16; return c.f;
}
__device__ __forceinline__ u16 f2bf(float f) {
  union { float f; unsigned u; } c; c.f = f;
  unsigned r = c.u + 0x7FFF + ((c.u >> 16) & 1);   // RNE
  return (u16)(r >> 16);
}
__device__ __forceinline__ unsigned pk2(float a, float b) {
  return (unsigned)f2bf(a) | ((unsigned)f2bf(b) << 16);
}
__device__ __forceinline__ float plo(unsigned p) {
  union { unsigned u; float f; } c; c.u = p << 16; return c.f;
}
__device__ __forceinline__ float phh(unsigned p) {
  union { unsigned u; float f; } c; c.u = p & 0xFFFF0000u; return c.f;
}
__device__ __forceinline__ void up8(uint4 p, float* o) {
  o[0] = plo(p.x); o[1] = phh(p.x); o[2] = plo(p.y); o[3] = phh(p.y);
  o[4] = plo(p.z); o[5] = phh(p.z); o[6] = plo(p.w); o[7] = phh(p.w);
}
__device__ __forceinline__ uint4 pk8(const float* o) {
  return make_uint4(pk2(o[0], o[1]), pk2(o[2], o[3]),
                    pk2(o[4], o[5]), pk2(o[6], o[7]));
}

// f(u) = log(clip(0.5*(1+erf(u)))) — table builder only
__device__ __forceinline__ float f_exact(float u) {
  float au = fabsf(u);
  float tt = __builtin_amdgcn_rcpf(fmaf(0.3275911f, au, 1.0f));
  float poly = tt * fmaf(tt, fmaf(tt, fmaf(tt, fmaf(tt, 1.061405429f,
                   -1.453152027f), 1.421413741f), -0.284496736f),
                   0.254829592f);
  float e = fmaf(-poly, __expf(-u * u), 1.0f);
  float erfu = (u < 0.0f) ? -e : e;
  float s = fmaf(0.5f, erfu, 0.5f);
  s = fminf(fmaxf(s, 1e-6f), 1.0f);
  return __logf(s);
}

// table over u in [-1.8, 2.2); last bin EXACTLY zero (bulk invariant).
__device__ __forceinline__ float tlook(const float2* __restrict__ ftab,
                                       float r2, float aoff, float hidu) {
  float r = sqrtf(r2 + 1e-12f);
  float t = fmaf(r, hidu, aoff);
  t = fminf(fmaxf(t, 0.0f), 511.75f);
  int j = (int)t;
  float fr = t - (float)j;
  float2 e = ftab[j];
  return fmaf(fr, e.y, e.x);
}

// ---------------------------------------------------------------------------
// Stage A (gather): one block per 8x8x8 tile, 2 z-cells/thread (acc[4][2]
// stays in VGPRs -- 8x32 tiles spilled to scratch, R9 regression). Writes
// fp32 eps (output) + bf16 ex/ey/ez packs. Empty tiles early-out.
// ---------------------------------------------------------------------------
__global__ __launch_bounds__(256) void eps_gather_kernel(
    const float* __restrict__ coords, const float* __restrict__ params,
    const int* __restrict__ num_atoms, float* __restrict__ eps_out,
    u16* __restrict__ exb, u16* __restrict__ eyb, u16* __restrict__ ezb,
    int N) {
  __shared__ float4 sat[SATN];
  __shared__ float2 ftab[TABN];
  __shared__ int scnt;

  const int xt = blockIdx.x, yt = blockIdx.y;
  const int bz = blockIdx.z;
  const int b = bz >> 4, zt = bz & 15;
  const int tid = threadIdx.x;

  const float u0 = -1.8f;
  const float du = (2.2f - u0) / (float)TABN;
  const float inv_du = (float)TABN / (2.2f - u0);
  const float hidu = 0.5f * inv_du;

  if (tid == 0) scnt = 0;
  __syncthreads();

  const float lox = (float)(xt * 8), hix = lox + 7.5f;
  const float loy = (float)(yt * 8), hiy = loy + 7.5f;
  const float loz = (float)(zt * 8), hiz = loz + 7.5f;

  const int na = num_atoms[b];
  for (int a = tid; a < N; a += 256) {
    if (a < na) {
      float ax = coords[(size_t)b * 3 * N + a * 3 + 0];
      float ay = coords[(size_t)b * 3 * N + a * 3 + 1];
      float az = coords[(size_t)b * 3 * N + a * 3 + 2];
      float rad = params[((size_t)b * N + a) * 2 + 1];
      float cx = fminf(fmaxf(ax, lox), hix);
      float cy = fminf(fmaxf(ay, loy), hiy);
      float cz = fminf(fmaxf(az, loz), hiz);
      float ddx = ax - cx, ddy = ay - cy, ddz = az - cz;
      float cut = rad + 5.85f;            // Rw + 4.4 (u<2.2) + slack
      if (ddx * ddx + ddy * ddy + ddz * ddz < cut * cut) {
        int s = atomicAdd(&scnt, 1);
        if (s < SATN) sat[s] = make_float4(ax, ay, az, rad);
      }
    }
  }
  __syncthreads();
  const int cnt = min(scnt, SATN);

  const int zq = tid & 3, yy = (tid >> 2) & 7, xx = tid >> 5;
  const int xi = xt * 8 + xx, yi = yt * 8 + yy, zi = zt * 8 + zq * 2;
  const int v = (xi << 14) + (yi << 7) + zi;
  const size_t eb = (size_t)b * 4 * MCELLS;
  const size_t cb = (size_t)b * MCELLS + v;

  if (cnt == 0) {
    const unsigned p79 = pk2(79.0f, 79.0f);
    *(float2*)(eps_out + eb + 0 * MCELLS + v) = make_float2(79.0f, 79.0f);
    *(float2*)(eps_out + eb + 1 * MCELLS + v) = make_float2(79.0f, 79.0f);
    *(float2*)(eps_out + eb + 2 * MCELLS + v) = make_float2(79.0f, 79.0f);
    *(float2*)(eps_out + eb + (size_t)3 * MCELLS + v) = make_float2(0.0f, 0.0f);
    *(unsigned*)(exb + cb) = p79;
    *(unsigned*)(eyb + cb) = p79;
    *(unsigned*)(ezb + cb) = p79;
    return;
  }

  for (int j = tid; j < TABN; j += 256) {
    float uj = fmaf(du, (float)j, u0);
    float f0 = f_exact(uj);
    float f1 = f_exact(uj + du);
    ftab[j] = (j == TABN - 1) ? make_float2(0.0f, 0.0f)
                              : make_float2(f0, f1 - f0);
  }
  __syncthreads();

  const float xf = (float)xi, yf = (float)yi, zf = (float)zi;
  float acc[4][2] = {{0.f, 0.f}, {0.f, 0.f}, {0.f, 0.f}, {0.f, 0.f}};

  for (int j = 0; j < cnt; ++j) {
    float4 A = sat[j];
    float dx = xf - A.x, dy = yf - A.y, dzb = zf - A.z;
    float Rw = A.w + 1.4f;
    float cw = Rw + 4.4f;                 // u < 2.2
    float cw2 = cw * cw;
    float aW = (1.8f - 0.5f * Rw) * inv_du;
    float aI = aW + 0.2f * inv_du;

    float dx2 = dx * dx, dxh = dx + 0.5f, dxh2 = dxh * dxh;
    float dy2 = dy * dy, dyh = dy + 0.5f, dyh2 = dyh * dyh;
    float mdx = fminf(dx2, dxh2);
    float mdy = fminf(dy2, dyh2);
    float zhi = dzb + 1.5f;
    float mdz = (dzb > 0.f) ? dzb * dzb : (zhi < 0.f ? zhi * zhi : 0.f);
    if (mdx + mdy + mdz >= cw2) continue;

#pragma unroll
    for (int k = 0; k < 2; ++k) {
      float dzv = dzb + (float)k;
      float dz2 = dzv * dzv, dzh = dzv + 0.5f, dzh2 = dzh * dzh;
      acc[0][k] += tlook(ftab, dxh2 + dy2 + dz2, aW, hidu);
      acc[1][k] += tlook(ftab, dx2 + dyh2 + dz2, aW, hidu);
      acc[2][k] += tlook(ftab, dx2 + dy2 + dzh2, aW, hidu);
      acc[3][k] += tlook(ftab, dx2 + dy2 + dz2, aI, hidu);
    }
  }

  float ev[4][2];
#pragma unroll
  for (int ch = 0; ch < 4; ++ch) {
    float e0 = __expf(acc[ch][0]), e1 = __expf(acc[ch][1]);
    if (ch < 3) {
      ev[ch][0] = fmaf(72.5f, e0, 6.5f);
      ev[ch][1] = fmaf(72.5f, e1, 6.5f);
    } else {
      ev[ch][0] = 1.0f - e0;
      ev[ch][1] = 1.0f - e1;
    }
    *(float2*)(eps_out + eb + (size_t)ch * MCELLS + v) =
        make_float2(ev[ch][0], ev[ch][1]);
  }
  *(unsigned*)(exb + cb) = pk2(ev[0][0], ev[0][1]);
  *(unsigned*)(eyb + cb) = pk2(ev[1][0], ev[1][1]);
  *(unsigned*)(ezb + cb) = pk2(ev[2][0], ev[2][1]);
}

// ---------------------------------------------------------------------------
// Stage B: trilinear charge scatter (CHARGE_CONV folded in).
// ---------------------------------------------------------------------------
__global__ __launch_bounds__(256) void q_scatter_kernel(
    const float* __restrict__ coords, const float* __restrict__ params,
    const int* __restrict__ num_atoms, float* __restrict__ q, int N, int B) {
  int t = blockIdx.x * blockDim.x + threadIdx.x;
  if (t >= B * N) return;
  int b = t / N, atom = t % N;
  if (atom >= num_atoms[b]) return;

  const float x = coords[(size_t)b * 3 * N + atom * 3 + 0];
  const float y = coords[(size_t)b * 3 * N + atom * 3 + 1];
  const float z = coords[(size_t)b * 3 * N + atom * 3 + 2];
  const float c = params[((size_t)b * N + atom) * 2 + 0] * 7046.52f;

  float fx0 = floorf(x), fy0 = floorf(y), fz0 = floorf(z);
  int ix = (int)fx0, iy = (int)fy0, iz = (int)fz0;
  float fx = x - fx0, fy = y - fy0, fz = z - fz0;

  float* __restrict__ g = q + (size_t)b * MCELLS;
  for (int k = 0; k < 8; ++k) {
    int cx = (k >> 2) & 1, cy = (k >> 1) & 1, cz = k & 1;
    int jx = ix + cx, jy = iy + cy, jz = iz + cz;
    if ((unsigned)jx >= (unsigned)BOX || (unsigned)jy >= (unsigned)BOX ||
        (unsigned)jz >= (unsigned)BOX) continue;
    float w = (cx ? fx : 1.0f - fx) * (cy ? fy : 1.0f - fy) *
              (cz ? fz : 1.0f - fz);
    atomicAdd(&g[(jx * BOX + jy) * BOX + jz], w * c);
  }
}

// ---------------------------------------------------------------------------
// Prep (8 cells/thread): reads bf16 ex/ey/ez (what the sweeps consume) +
// fp32 lm/q; writes rdn, rq2, phiA (=rq), purity bytes.
// ---------------------------------------------------------------------------
__global__ __launch_bounds__(256) void prep8_kernel(
    const float* __restrict__ eps, const float* __restrict__ q,
    const u16* __restrict__ exb, const u16* __restrict__ eyb,
    const u16* __restrict__ ezb,
    u16* __restrict__ rdn, u16* __restrict__ rq2, u16* __restrict__ phiA,
    unsigned char* __restrict__ pure, int B) {
  const int per_b = MCELLS / 8;   // 2^18
  int t = blockIdx.x * 256 + threadIdx.x;
  if (t >= B * per_b) return;
  int b = t >> 18;
  int r = t & (per_b - 1);
  int zg = r & 15, y = (r >> 4) & 127, x = r >> 11;
  int z0 = zg << 3;
  int v = (x << 14) | (y << 7) | z0;
  size_t cell = (size_t)b * MCELLS + v;

  const float* lm = eps + (size_t)(b * 4 + 3) * MCELLS;
  const uint4 z4 = make_uint4(0, 0, 0, 0);

  uint4 ec = *(const uint4*)(exb + cell);
  uint4 yc = *(const uint4*)(eyb + cell);
  uint4 zc = *(const uint4*)(ezb + cell);
  uint4 em = (x > 0) ? *(const uint4*)(exb + cell - 16384) : z4;
  uint4 ym = (y > 0) ? *(const uint4*)(eyb + cell - 128) : z4;
  u16 ezm0 = (z0 > 0) ? ezb[cell - 1] : (u16)0;

  float exA[8], eyA[8], xmA[8], ymA[8], ezA9[9], lA[8], qA[8];
  up8(ec, exA); up8(yc, eyA); up8(em, xmA); up8(ym, ymA);
  ezA9[0] = bf2f(ezm0); up8(zc, ezA9 + 1);
  *(float4*)(lA)     = *(const float4*)(lm + v);
  *(float4*)(lA + 4) = *(const float4*)(lm + v + 4);
  *(float4*)(qA)     = *(const float4*)(q + cell);
  *(float4*)(qA + 4) = *(const float4*)(q + cell + 4);

  float rdA[8], rqA[8];
  bool pu = true;
#pragma unroll
  for (int i = 0; i < 8; ++i) {
    float den = exA[i] + xmA[i] + eyA[i] + ymA[i] + ezA9[i + 1] + ezA9[i] +
                0.106f * lA[i];
    rdA[i] = __builtin_amdgcn_rcpf(den);
    rqA[i] = qA[i] * rdA[i];
    pu &= (exA[i] == 79.0f) & (eyA[i] == 79.0f) & (ezA9[i + 1] == 79.0f) &
          (lA[i] == 0.0f) & (qA[i] == 0.0f);
  }
  *(uint4*)(rdn + cell) = pk8(rdA);
  uint4 rqp = pk8(rqA);
  *(uint4*)(rq2 + cell) = rqp;
  *(uint4*)(phiA + cell) = rqp;   // phi after sweep 1 (phi0 = 0)

  unsigned long long bal = __ballot(pu);
  int lane = threadIdx.x & 63;
  if ((lane & 15) == 0) {
    unsigned m = (unsigned)((bal >> (lane & 48)) & 0xFFFFull);
    pure[((size_t)b << 14) + (x << 7) + y] = (m == 0xFFFFu) ? 1 : 0;
  }
}

// bulk flag per (x, y-quad) for the single final sweep
__global__ __launch_bounds__(256) void flag_kernel(
    const unsigned char* __restrict__ pure, unsigned char* __restrict__ flags,
    int B) {
  int t = blockIdx.x * 256 + threadIdx.x;
  if (t >= B * 128 * 32) return;
  int b = t >> 12;
  int r = t & 4095;
  int x = r >> 5, yq = r & 31;
  unsigned char f = 0;
  if (x > 0 && x < 127 && yq > 0 && yq < 31) {
    const unsigned char* P = pure + ((size_t)b << 14);
    bool ok = true;
    int y0 = yq << 2;
    for (int dx = -1; dx <= 1; ++dx)
      for (int yy = y0 - 1; yy <= y0 + 4; ++yy)
        ok &= (P[(x + dx) * 128 + yy] != 0);
    f = ok ? 1 : 0;
  }
  flags[t] = f;
}

// ---------------------------------------------------------------------------
// 8-z-cell stencil step reading phi from an LDS tile.
// ---------------------------------------------------------------------------
__device__ __forceinline__ void stage8(
    const u16* __restrict__ sp, int cst, int c0, int z0, size_t cell,
    int gx, int gy, bool bulk,
    const u16* __restrict__ exb, const u16* __restrict__ eyb,
    const u16* __restrict__ ezb, const u16* __restrict__ rdn,
    const u16* __restrict__ rq2, float* o) {
  const u16* pc0 = sp + (c0 << 7) + z0;
  uint4 pc = *(const uint4*)pc0;
  u16 zmu = (z0 > 0)   ? pc0[-1] : (u16)0;
  u16 zpu = (z0 < 120) ? pc0[8]  : (u16)0;
  uint4 xp = *(const uint4*)(pc0 + (cst << 7));
  uint4 xm = *(const uint4*)(pc0 - (cst << 7));
  uint4 yp = *(const uint4*)(pc0 + 128);
  uint4 ym = *(const uint4*)(pc0 - 128);

  float pz[10];
  pz[0] = bf2f(zmu); up8(pc, pz + 1); pz[9] = bf2f(zpu);
  float xpA[8], xmA[8], ypA[8], ymA[8];
  up8(xp, xpA); up8(xm, xmA); up8(yp, ypA); up8(ym, ymA);

  if (bulk) {
    float rdc  = bf2f(f2bf(__builtin_amdgcn_rcpf(474.0f)));   // 6*79
    float rdc0 = bf2f(f2bf(__builtin_amdgcn_rcpf(395.0f)));   // z=0
#pragma unroll
    for (int i = 0; i < 8; ++i) {
      float s = xpA[i] + xmA[i] + ypA[i] + ymA[i] + pz[i] + pz[i + 2];
      float rd = (z0 + i == 0) ? rdc0 : rdc;
      o[i] = rd * (79.0f * s);
    }
  } else {
    const uint4 z4 = make_uint4(0, 0, 0, 0);
    uint4 ec  = *(const uint4*)(exb + cell);
    uint4 em  = (gx > 0) ? *(const uint4*)(exb + cell - 16384) : z4;
    uint4 yc  = *(const uint4*)(eyb + cell);
    uint4 ym4 = (gy > 0) ? *(const uint4*)(eyb + cell - 128) : z4;
    uint4 zc  = *(const uint4*)(ezb + cell);
    u16 ezm0  = (z0 > 0) ? ezb[cell - 1] : (u16)0;
    uint4 rd4 = *(const uint4*)(rdn + cell);
    uint4 rq4 = *(const uint4*)(rq2 + cell);
    float exA[8], exmA[8], eyA[8], eymA[8], ezA[9], rdA[8], rqA[8];
    up8(ec, exA); up8(em, exmA); up8(yc, eyA); up8(ym4, eymA);
    ezA[0] = bf2f(ezm0); up8(zc, ezA + 1);
    up8(rd4, rdA); up8(rq4, rqA);
#pragma unroll
    for (int i = 0; i < 8; ++i) {
      float num = exA[i] * xpA[i];
      num = fmaf(exmA[i], xmA[i], num);
      num = fmaf(eyA[i],  ypA[i], num);
      num = fmaf(eymA[i], ymA[i], num);
      num = fmaf(ezA[i + 1], pz[i + 2], num);
      num = fmaf(ezA[i],     pz[i],     num);
      o[i] = fmaf(rdA[i], num, rqA[i]);
    }
  }
}

// ---------------------------------------------------------------------------
// Fused double sweep with XCD-aware block swizzle: flat%8 selects XCD
// (round-robin dispatch heuristic); each XCD owns a fixed 16-cell x-slab so
// its coefficient slab (~5 MB) stays hot in its private L2 across all 14
// dispatches. Correctness independent of the actual mapping.
// ---------------------------------------------------------------------------
__global__ __launch_bounds__(256) void fused2_kernel(
    const u16* __restrict__ pin, u16* __restrict__ pout,
    const u16* __restrict__ exb, const u16* __restrict__ eyb,
    const u16* __restrict__ ezb, const u16* __restrict__ rdn,
    const u16* __restrict__ rq2, const unsigned char* __restrict__ pure) {
  __shared__ u16 s0[12 * 12 * 128];
  __shared__ u16 s1[10 * 10 * 128];
  __shared__ unsigned char sbulk[144];

  const int flat = blockIdx.x;
  const int xcd = flat & 7;
  const int idx = flat >> 3;
  const int x0 = (((xcd << 1) | (idx & 1))) * 8;
  const int rem = idx >> 1;
  const int y0 = (rem & 15) * 8;
  const int b = rem >> 4;

  const int tid = threadIdx.x;
  const size_t bbase = (size_t)b << 21;
  const uint4 z4 = make_uint4(0, 0, 0, 0);

  if (tid < 144) {
    int cx = tid / 12, cy = tid - (tid / 12) * 12;
    int gx = x0 - 2 + cx, gy = y0 - 2 + cy;
    bool ok = false;
    if (gx >= 1 && gx <= 126 && gy >= 1 && gy <= 126) {
      const unsigned char* P = pure + ((size_t)b << 14);
      ok = P[(gx << 7) + gy] && P[((gx - 1) << 7) + gy] &&
           P[((gx + 1) << 7) + gy] && P[(gx << 7) + gy - 1] &&
           P[(gx << 7) + gy + 1];
    }
    sbulk[tid] = ok ? 1 : 0;
  }

  for (int i = tid; i < 144 * 16; i += 256) {
    int col = i >> 4, zc = i & 15;
    int cx = col / 12, cy = col - (col / 12) * 12;
    int gx = x0 - 2 + cx, gy = y0 - 2 + cy;
    uint4 vv = z4;
    if ((unsigned)gx < 128u && (unsigned)gy < 128u)
      vv = *(const uint4*)(pin + (bbase | (gx << 14) | (gy << 7) | (zc << 3)));
    ((uint4*)s0)[(col << 4) + zc] = vv;
  }
  __syncthreads();

  for (int u = tid; u < 100 * 16; u += 256) {
    int col = u >> 4, zc = u & 15, zz = zc << 3;
    int cx = col / 10, cy = col - (col / 10) * 10;
    int gx = x0 - 1 + cx, gy = y0 - 1 + cy;
    uint4* dst = (uint4*)(s1 + (col << 7) + zz);
    if ((unsigned)gx >= 128u || (unsigned)gy >= 128u) { *dst = z4; continue; }
    int c0 = (cx + 1) * 12 + (cy + 1);
    size_t cell = bbase | (gx << 14) | (gy << 7) | zz;
    float o[8];
    stage8(s0, 12, c0, zz, cell, gx, gy, sbulk[c0] != 0,
           exb, eyb, ezb, rdn, rq2, o);
    *dst = pk8(o);
  }
  __syncthreads();

  for (int u = tid; u < 64 * 16; u += 256) {
    int col = u >> 4, zc = u & 15, zz = zc << 3;
    int cx = col >> 3, cy = col & 7;
    int gx = x0 + cx, gy = y0 + cy;
    int c1 = (cx + 1) * 10 + (cy + 1);
    size_t cell = bbase | (gx << 14) | (gy << 7) | zz;
    float o[8];
    stage8(s1, 10, c1, zz, cell, gx, gy,
           sbulk[(cx + 2) * 12 + (cy + 2)] != 0, exb, eyb, ezb, rdn, rq2, o);
    *(uint4*)(pout + cell) = pk8(o);
  }
}

// ---------------------------------------------------------------------------
// Single sweep (final): fp32 write to d_out.
// ---------------------------------------------------------------------------
__global__ __launch_bounds__(256) void sweep_final_kernel(
    const u16* __restrict__ pin, float* __restrict__ poutf,
    const u16* __restrict__ exb, const u16* __restrict__ eyb,
    const u16* __restrict__ ezb, const u16* __restrict__ rdn,
    const u16* __restrict__ rq2, const unsigned char* __restrict__ flags,
    int units) {
  int t = blockIdx.x * 256 + threadIdx.x;
  if (t >= units) return;
  int b = t >> 18;
  int r = t & ((1 << 18) - 1);
  int zg = r & 15, y = (r >> 4) & 127, x = r >> 11;
  int z0 = zg << 3;
  int v = (x << 14) | (y << 7) | z0;
  size_t cell = (size_t)b * MCELLS + v;

  const uint4 z4 = make_uint4(0, 0, 0, 0);
  uint4 pc = *(const uint4*)(pin + cell);
  u16 zmu = (z0 > 0)   ? pin[cell - 1] : (u16)0;
  u16 zpu = (z0 < 120) ? pin[cell + 8] : (u16)0;
  uint4 xp = (x < 127) ? *(const uint4*)(pin + cell + 16384) : z4;
  uint4 xm = (x > 0)   ? *(const uint4*)(pin + cell - 16384) : z4;
  uint4 yp = (y < 127) ? *(const uint4*)(pin + cell + 128) : z4;
  uint4 ym = (y > 0)   ? *(const uint4*)(pin + cell - 128) : z4;

  float pz[10];
  pz[0] = bf2f(zmu); up8(pc, pz + 1); pz[9] = bf2f(zpu);
  float xpA[8], xmA[8], ypA[8], ymA[8];
  up8(xp, xpA); up8(xm, xmA); up8(yp, ypA); up8(ym, ymA);

  bool bulk = flags[(b << 12) + (x << 5) + (y >> 2)] != 0;

  float o[8];
  if (bulk) {
    float rdc  = bf2f(f2bf(__builtin_amdgcn_rcpf(474.0f)));
    float rdc0 = bf2f(f2bf(__builtin_amdgcn_rcpf(395.0f)));
#pragma unroll
    for (int i = 0; i < 8; ++i) {
      float s = xpA[i] + xmA[i] + ypA[i] + ymA[i] + pz[i] + pz[i + 2];
      float rd = (z0 + i == 0) ? rdc0 : rdc;
      o[i] = rd * (79.0f * s);
    }
  } else {
    uint4 ec  = *(const uint4*)(exb + cell);
    uint4 em  = (x > 0) ? *(const uint4*)(exb + cell - 16384) : z4;
    uint4 yc  = *(const uint4*)(eyb + cell);
    uint4 ym4 = (y > 0) ? *(const uint4*)(eyb + cell - 128) : z4;
    uint4 zc  = *(const uint4*)(ezb + cell);
    u16 ezm0  = (z0 > 0) ? ezb[cell - 1] : (u16)0;
    uint4 rd4 = *(const uint4*)(rdn + cell);
    uint4 rq4 = *(const uint4*)(rq2 + cell);
    float exA[8], exmA[8], eyA[8], eymA[8], ezA[9], rdA[8], rqA[8];
    up8(ec, exA); up8(em, exmA); up8(yc, eyA); up8(ym4, eymA);
    ezA[0] = bf2f(ezm0); up8(zc, ezA + 1);
    up8(rd4, rdA); up8(rq4, rqA);
#pragma unroll
    for (int i = 0; i < 8; ++i) {
      float num = exA[i] * xpA[i];
      num = fmaf(exmA[i], xmA[i], num);
      num = fmaf(eyA[i],  ypA[i], num);
      num = fmaf(eymA[i], ymA[i], num);
      num = fmaf(ezA[i + 1], pz[i + 2], num);
      num = fmaf(ezA[i],     pz[i],     num);
      o[i] = fmaf(rdA[i], num, rqA[i]);
    }
  }
  *(float4*)(poutf + cell)     = make_float4(o[0], o[1], o[2], o[3]);
  *(float4*)(poutf + cell + 4) = make_float4(o[4], o[5], o[6], o[7]);
}

// ---------------------------------------------------------------------------
// Fallback fp32 Jacobi (tiny ws)
// ---------------------------------------------------------------------------
__global__ __launch_bounds__(256) void jacobi_kernel(
    const float* __restrict__ phi_in, float* __restrict__ phi_out,
    const float* __restrict__ eps, const float* __restrict__ rhs, int B) {
  int i = blockIdx.x * blockDim.x + threadIdx.x;
  if (i >= B * MCELLS) return;
  int b = i >> 21;
  int v = i & (MCELLS - 1);
  int z = v & 127, y = (v >> 7) & 127, x = v >> 14;

  const float* ex = eps + (size_t)(b * 4 + 0) * MCELLS;
  const float* ey = eps + (size_t)(b * 4 + 1) * MCELLS;
  const float* ez = eps + (size_t)(b * 4 + 2) * MCELLS;
  const float* lm = eps + (size_t)(b * 4 + 3) * MCELLS;
  const float* p  = phi_in + (size_t)b * MCELLS;

  float exc = ex[v], eyc = ey[v], ezc = ez[v];
  float exm = (x > 0) ? ex[v - BOX * BOX] : 0.0f;
  float eym = (y > 0) ? ey[v - BOX]       : 0.0f;
  float ezm = (z > 0) ? ez[v - 1]         : 0.0f;

  float num = rhs[i];
  num += (x < BOX - 1) ? exc * p[v + BOX * BOX] : 0.0f;
  num += (x > 0)       ? exm * p[v - BOX * BOX] : 0.0f;
  num += (y < BOX - 1) ? eyc * p[v + BOX]       : 0.0f;
  num += (y > 0)       ? eym * p[v - BOX]       : 0.0f;
  num += (z < BOX - 1) ? ezc * p[v + 1]         : 0.0f;
  num += (z > 0)       ? ezm * p[v - 1]         : 0.0f;

  float den = exc + exm + eyc + eym + ezc + ezm + 0.106f * lm[v];
  phi_out[i] = num / den;
}

// ---------------------------------------------------------------------------
extern "C" void kernel_launch(void* const* d_in, const int* in_sizes, int n_in,
                              void* d_out, int out_size, void* d_ws,
                              size_t ws_size, hipStream_t stream) {
  const float* coords    = (const float*)d_in[0];
  const float* params    = (const float*)d_in[1];
  const int*   num_atoms = (const int*)d_in[2];

  const int B = in_sizes[2];
  const int N = in_sizes[1] / (2 * B);

  float* out = (float*)d_out;
  float* q   = out;                            // (B, M)
  float* eps = out + (size_t)B * MCELLS;       // (B, 4, M)
  float* phi = out + (size_t)B * MCELLS * 5;   // (B, M)

  const size_t BM = (size_t)B * MCELLS;
  u16* phiA = (u16*)d_ws;
  u16* phiB = phiA + BM;
  u16* exb  = phiB + BM;
  u16* eyb  = exb + BM;
  u16* ezb  = eyb + BM;
  u16* rdn  = ezb + BM;
  u16* rq2  = rdn + BM;
  unsigned char* pureb = (unsigned char*)(rq2 + BM);
  unsigned char* flags = pureb + (size_t)B * 16384;
  const size_t need = BM * 14 + (size_t)B * (16384 + 4096);

  const bool fast = (ws_size >= need);

  hipMemsetAsync(q, 0, sizeof(float) * BM, stream);   // scatter accumulator

  eps_gather_kernel<<<dim3(16, 16, 16 * B), 256, 0, stream>>>(
      coords, params, num_atoms, eps,
      fast ? exb : (u16*)d_ws, fast ? eyb : (u16*)d_ws,
      fast ? ezb : (u16*)d_ws, N);
  q_scatter_kernel<<<(B * N + 255) / 256, 256, 0, stream>>>(
      coords, params, num_atoms, q, N, B);

  if (fast) {
    const int pblocks = B * 1024;
    prep8_kernel<<<pblocks, 256, 0, stream>>>(eps, q, exb, eyb, ezb, rdn, rq2,
                                              phiA, pureb, B);
    flag_kernel<<<(B * 4096 + 255) / 256, 256, 0, stream>>>(pureb, flags, B);

    // prep did sweep 1 (phi1 in phiA). 14 fused pairs = sweeps 2..29,
    // ping-pong A->B->A (phi29 ends in A). Final single sweep 30 -> fp32 out.
    u16* pa = phiA;
    u16* pb = phiB;
    for (int k = 0; k < 14; ++k) {
      fused2_kernel<<<256 * B, 256, 0, stream>>>(
          pa, pb, exb, eyb, ezb, rdn, rq2, pureb);
      u16* tmp = pa; pa = pb; pb = tmp;
    }
    const int units = B * (MCELLS / 8);
    sweep_final_kernel<<<(units + 255) / 256, 256, 0, stream>>>(
        pa, phi, exb, eyb, ezb, rdn, rq2, flags, units);
  } else {
    hipMemsetAsync(phi, 0, sizeof(float) * BM, stream);
    float* pa = phi;
    float* pb = (float*)d_ws;
    int total = (int)BM;
    for (int it = 0; it < 30; ++it) {
      jacobi_kernel<<<(total + 255) / 256, 256, 0, stream>>>(pa, pb, eps, q, B);
      float* tmp = pa; pa = pb; pb = tmp;
    }
  }
}

// Round 11
// 506.617 us; speedup vs baseline: 1.2706x; 1.0934x over previous
//
#include <hip/hip_runtime.h>
#include <math.h>

#define BOX 128
#define MCELLS (BOX*BOX*BOX)
#define TABN 512
#define SATN 256
typedef unsigned short u16;

__device__ __forceinline__ float bf2f(u16 h) {
  union { unsigned u; float f; } c; c.u = ((unsigned)h) << 16; return c.f;
}
__device__ __forceinline__ u16 f2bf(float f) {
  union { float f; unsigned u; } c; c.f = f;
  unsigned r = c.u + 0x7FFF + ((c.u >> 16) & 1);   // RNE
  return (u16)(r >> 16);
}
__device__ __forceinline__ unsigned pk2(float a, float b) {
  return (unsigned)f2bf(a) | ((unsigned)f2bf(b) << 16);
}
__device__ __forceinline__ float plo(unsigned p) {
  union { unsigned u; float f; } c; c.u = p << 16; return c.f;
}
__device__ __forceinline__ float phh(unsigned p) {
  union { unsigned u; float f; } c; c.u = p & 0xFFFF0000u; return c.f;
}
__device__ __forceinline__ void up8(uint4 p, float* o) {
  o[0] = plo(p.x); o[1] = phh(p.x); o[2] = plo(p.y); o[3] = phh(p.y);
  o[4] = plo(p.z); o[5] = phh(p.z); o[6] = plo(p.w); o[7] = phh(p.w);
}
__device__ __forceinline__ uint4 pk8(const float* o) {
  return make_uint4(pk2(o[0], o[1]), pk2(o[2], o[3]),
                    pk2(o[4], o[5]), pk2(o[6], o[7]));
}

// f(u) = log(clip(0.5*(1+erf(u)))) — table builder only
__device__ __forceinline__ float f_exact(float u) {
  float au = fabsf(u);
  float tt = __builtin_amdgcn_rcpf(fmaf(0.3275911f, au, 1.0f));
  float poly = tt * fmaf(tt, fmaf(tt, fmaf(tt, fmaf(tt, 1.061405429f,
                   -1.453152027f), 1.421413741f), -0.284496736f),
                   0.254829592f);
  float e = fmaf(-poly, __expf(-u * u), 1.0f);
  float erfu = (u < 0.0f) ? -e : e;
  float s = fmaf(0.5f, erfu, 0.5f);
  s = fminf(fmaxf(s, 1e-6f), 1.0f);
  return __logf(s);
}

// table over u in [-1.8, 2.2); last bin EXACTLY zero (bulk invariant).
__device__ __forceinline__ float tlook(const float2* __restrict__ ftab,
                                       float r2, float aoff, float hidu) {
  float r = sqrtf(r2 + 1e-12f);
  float t = fmaf(r, hidu, aoff);
  t = fminf(fmaxf(t, 0.0f), 511.75f);
  int j = (int)t;
  float fr = t - (float)j;
  float2 e = ftab[j];
  return fmaf(fr, e.y, e.x);
}

// ---------------------------------------------------------------------------
// Stage A (gather): one block per 8x8x8 tile, 2 z-cells/thread (R8 known-
// good config: VGPR 24, no spill). fp32 eps writes only — bf16 packs are
// produced by prep8 with coalesced full-line writes (R10's in-kernel 4B
// pack stores caused partial-line write amplification, WRITE 78->144 MB).
// ---------------------------------------------------------------------------
__global__ __launch_bounds__(256) void eps_gather_kernel(
    const float* __restrict__ coords, const float* __restrict__ params,
    const int* __restrict__ num_atoms, float* __restrict__ eps_out, int N) {
  __shared__ float4 sat[SATN];
  __shared__ float2 ftab[TABN];
  __shared__ int scnt;

  const int xt = blockIdx.x, yt = blockIdx.y;
  const int bz = blockIdx.z;
  const int b = bz >> 4, zt = bz & 15;
  const int tid = threadIdx.x;

  const float u0 = -1.8f;
  const float du = (2.2f - u0) / (float)TABN;
  const float inv_du = (float)TABN / (2.2f - u0);
  const float hidu = 0.5f * inv_du;

  if (tid == 0) scnt = 0;
  __syncthreads();

  const float lox = (float)(xt * 8), hix = lox + 7.5f;
  const float loy = (float)(yt * 8), hiy = loy + 7.5f;
  const float loz = (float)(zt * 8), hiz = loz + 7.5f;

  const int na = num_atoms[b];
  for (int a = tid; a < N; a += 256) {
    if (a < na) {
      float ax = coords[(size_t)b * 3 * N + a * 3 + 0];
      float ay = coords[(size_t)b * 3 * N + a * 3 + 1];
      float az = coords[(size_t)b * 3 * N + a * 3 + 2];
      float rad = params[((size_t)b * N + a) * 2 + 1];
      float cx = fminf(fmaxf(ax, lox), hix);
      float cy = fminf(fmaxf(ay, loy), hiy);
      float cz = fminf(fmaxf(az, loz), hiz);
      float ddx = ax - cx, ddy = ay - cy, ddz = az - cz;
      float cut = rad + 5.85f;            // Rw + 4.4 (u<2.2) + slack
      if (ddx * ddx + ddy * ddy + ddz * ddz < cut * cut) {
        int s = atomicAdd(&scnt, 1);
        if (s < SATN) sat[s] = make_float4(ax, ay, az, rad);
      }
    }
  }
  __syncthreads();
  const int cnt = min(scnt, SATN);

  const int zq = tid & 3, yy = (tid >> 2) & 7, xx = tid >> 5;
  const int xi = xt * 8 + xx, yi = yt * 8 + yy, zi = zt * 8 + zq * 2;
  const int v = (xi << 14) + (yi << 7) + zi;
  const size_t eb = (size_t)b * 4 * MCELLS;

  if (cnt == 0) {
    *(float2*)(eps_out + eb + 0 * MCELLS + v) = make_float2(79.0f, 79.0f);
    *(float2*)(eps_out + eb + 1 * MCELLS + v) = make_float2(79.0f, 79.0f);
    *(float2*)(eps_out + eb + 2 * MCELLS + v) = make_float2(79.0f, 79.0f);
    *(float2*)(eps_out + eb + (size_t)3 * MCELLS + v) = make_float2(0.0f, 0.0f);
    return;
  }

  for (int j = tid; j < TABN; j += 256) {
    float uj = fmaf(du, (float)j, u0);
    float f0 = f_exact(uj);
    float f1 = f_exact(uj + du);
    ftab[j] = (j == TABN - 1) ? make_float2(0.0f, 0.0f)
                              : make_float2(f0, f1 - f0);
  }
  __syncthreads();

  const float xf = (float)xi, yf = (float)yi, zf = (float)zi;
  float acc[4][2] = {{0.f, 0.f}, {0.f, 0.f}, {0.f, 0.f}, {0.f, 0.f}};

  for (int j = 0; j < cnt; ++j) {
    float4 A = sat[j];
    float dx = xf - A.x, dy = yf - A.y, dzb = zf - A.z;
    float Rw = A.w + 1.4f;
    float cw = Rw + 4.4f;                 // u < 2.2
    float cw2 = cw * cw;
    float aW = (1.8f - 0.5f * Rw) * inv_du;
    float aI = aW + 0.2f * inv_du;

    float dx2 = dx * dx, dxh = dx + 0.5f, dxh2 = dxh * dxh;
    float dy2 = dy * dy, dyh = dy + 0.5f, dyh2 = dyh * dyh;
    float mdx = fminf(dx2, dxh2);
    float mdy = fminf(dy2, dyh2);
    float zhi = dzb + 1.5f;
    float mdz = (dzb > 0.f) ? dzb * dzb : (zhi < 0.f ? zhi * zhi : 0.f);
    if (mdx + mdy + mdz >= cw2) continue;

#pragma unroll
    for (int k = 0; k < 2; ++k) {
      float dzv = dzb + (float)k;
      float dz2 = dzv * dzv, dzh = dzv + 0.5f, dzh2 = dzh * dzh;
      acc[0][k] += tlook(ftab, dxh2 + dy2 + dz2, aW, hidu);
      acc[1][k] += tlook(ftab, dx2 + dyh2 + dz2, aW, hidu);
      acc[2][k] += tlook(ftab, dx2 + dy2 + dzh2, aW, hidu);
      acc[3][k] += tlook(ftab, dx2 + dy2 + dz2, aI, hidu);
    }
  }

#pragma unroll
  for (int ch = 0; ch < 4; ++ch) {
    float e0 = __expf(acc[ch][0]), e1 = __expf(acc[ch][1]);
    float2 o = (ch < 3)
        ? make_float2(fmaf(72.5f, e0, 6.5f), fmaf(72.5f, e1, 6.5f))
        : make_float2(1.0f - e0, 1.0f - e1);
    *(float2*)(eps_out + eb + (size_t)ch * MCELLS + v) = o;
  }
}

// ---------------------------------------------------------------------------
// Stage B: trilinear charge scatter (CHARGE_CONV folded in).
// ---------------------------------------------------------------------------
__global__ __launch_bounds__(256) void q_scatter_kernel(
    const float* __restrict__ coords, const float* __restrict__ params,
    const int* __restrict__ num_atoms, float* __restrict__ q, int N, int B) {
  int t = blockIdx.x * blockDim.x + threadIdx.x;
  if (t >= B * N) return;
  int b = t / N, atom = t % N;
  if (atom >= num_atoms[b]) return;

  const float x = coords[(size_t)b * 3 * N + atom * 3 + 0];
  const float y = coords[(size_t)b * 3 * N + atom * 3 + 1];
  const float z = coords[(size_t)b * 3 * N + atom * 3 + 2];
  const float c = params[((size_t)b * N + atom) * 2 + 0] * 7046.52f;

  float fx0 = floorf(x), fy0 = floorf(y), fz0 = floorf(z);
  int ix = (int)fx0, iy = (int)fy0, iz = (int)fz0;
  float fx = x - fx0, fy = y - fy0, fz = z - fz0;

  float* __restrict__ g = q + (size_t)b * MCELLS;
  for (int k = 0; k < 8; ++k) {
    int cx = (k >> 2) & 1, cy = (k >> 1) & 1, cz = k & 1;
    int jx = ix + cx, jy = iy + cy, jz = iz + cz;
    if ((unsigned)jx >= (unsigned)BOX || (unsigned)jy >= (unsigned)BOX ||
        (unsigned)jz >= (unsigned)BOX) continue;
    float w = (cx ? fx : 1.0f - fx) * (cy ? fy : 1.0f - fy) *
              (cz ? fz : 1.0f - fz);
    atomicAdd(&g[(jx * BOX + jy) * BOX + jz], w * c);
  }
}

// ---------------------------------------------------------------------------
// Prep (8 cells/thread): reads fp32 eps + q (coalesced); writes bf16 packs
// ex/ey/ez/rd/rq, phiA = rq (sweep 1), and per-column purity bytes.
// ---------------------------------------------------------------------------
__global__ __launch_bounds__(256) void prep8_kernel(
    const float* __restrict__ eps, const float* __restrict__ q,
    u16* __restrict__ exb, u16* __restrict__ eyb, u16* __restrict__ ezb,
    u16* __restrict__ rdn, u16* __restrict__ rq2, u16* __restrict__ phiA,
    unsigned char* __restrict__ pure, int B) {
  const int per_b = MCELLS / 8;   // 2^18
  int t = blockIdx.x * 256 + threadIdx.x;
  if (t >= B * per_b) return;
  int b = t >> 18;
  int r = t & (per_b - 1);
  int zg = r & 15, y = (r >> 4) & 127, x = r >> 11;
  int z0 = zg << 3;
  int v = (x << 14) | (y << 7) | z0;
  size_t cell = (size_t)b * MCELLS + v;

  const float* ex = eps + (size_t)(b * 4 + 0) * MCELLS;
  const float* ey = eps + (size_t)(b * 4 + 1) * MCELLS;
  const float* ez = eps + (size_t)(b * 4 + 2) * MCELLS;
  const float* lm = eps + (size_t)(b * 4 + 3) * MCELLS;

  float exA[8], eyA[8], ezA9[9], lA[8], qA[8], xmA[8], ymA[8];
  *(float4*)(exA)     = *(const float4*)(ex + v);
  *(float4*)(exA + 4) = *(const float4*)(ex + v + 4);
  *(float4*)(eyA)     = *(const float4*)(ey + v);
  *(float4*)(eyA + 4) = *(const float4*)(ey + v + 4);
  *(float4*)(ezA9 + 1) = *(const float4*)(ez + v);
  *(float4*)(ezA9 + 5) = *(const float4*)(ez + v + 4);
  ezA9[0] = (z0 > 0) ? ez[v - 1] : 0.0f;
  *(float4*)(lA)     = *(const float4*)(lm + v);
  *(float4*)(lA + 4) = *(const float4*)(lm + v + 4);
  *(float4*)(qA)     = *(const float4*)(q + cell);
  *(float4*)(qA + 4) = *(const float4*)(q + cell + 4);
  if (x > 0) {
    *(float4*)(xmA)     = *(const float4*)(ex + v - 16384);
    *(float4*)(xmA + 4) = *(const float4*)(ex + v - 16384 + 4);
  } else {
#pragma unroll
    for (int i = 0; i < 8; ++i) xmA[i] = 0.0f;
  }
  if (y > 0) {
    *(float4*)(ymA)     = *(const float4*)(ey + v - 128);
    *(float4*)(ymA + 4) = *(const float4*)(ey + v - 128 + 4);
  } else {
#pragma unroll
    for (int i = 0; i < 8; ++i) ymA[i] = 0.0f;
  }

  float rdA[8], rqA[8];
  bool pu = true;
#pragma unroll
  for (int i = 0; i < 8; ++i) {
    float den = exA[i] + xmA[i] + eyA[i] + ymA[i] + ezA9[i + 1] + ezA9[i] +
                0.106f * lA[i];
    rdA[i] = __builtin_amdgcn_rcpf(den);
    rqA[i] = qA[i] * rdA[i];
    pu &= (exA[i] == 79.0f) & (eyA[i] == 79.0f) & (ezA9[i + 1] == 79.0f) &
          (lA[i] == 0.0f) & (qA[i] == 0.0f);
  }
  *(uint4*)(exb + cell) = pk8(exA);
  *(uint4*)(eyb + cell) = pk8(eyA);
  *(uint4*)(ezb + cell) = pk8(ezA9 + 1);
  *(uint4*)(rdn + cell) = pk8(rdA);
  uint4 rqp = pk8(rqA);
  *(uint4*)(rq2 + cell) = rqp;
  *(uint4*)(phiA + cell) = rqp;   // phi after sweep 1 (phi0 = 0)

  unsigned long long bal = __ballot(pu);
  int lane = threadIdx.x & 63;
  if ((lane & 15) == 0) {
    unsigned m = (unsigned)((bal >> (lane & 48)) & 0xFFFFull);
    pure[((size_t)b << 14) + (x << 7) + y] = (m == 0xFFFFu) ? 1 : 0;
  }
}

// bulk flag per (x, y-quad) for the single final sweep
__global__ __launch_bounds__(256) void flag_kernel(
    const unsigned char* __restrict__ pure, unsigned char* __restrict__ flags,
    int B) {
  int t = blockIdx.x * 256 + threadIdx.x;
  if (t >= B * 128 * 32) return;
  int b = t >> 12;
  int r = t & 4095;
  int x = r >> 5, yq = r & 31;
  unsigned char f = 0;
  if (x > 0 && x < 127 && yq > 0 && yq < 31) {
    const unsigned char* P = pure + ((size_t)b << 14);
    bool ok = true;
    int y0 = yq << 2;
    for (int dx = -1; dx <= 1; ++dx)
      for (int yy = y0 - 1; yy <= y0 + 4; ++yy)
        ok &= (P[(x + dx) * 128 + yy] != 0);
    f = ok ? 1 : 0;
  }
  flags[t] = f;
}

// ---------------------------------------------------------------------------
// 8-z-cell stencil step reading phi from an LDS tile (cst = x-column
// stride in columns; y stride is 1 column = 128 cells).
// ---------------------------------------------------------------------------
__device__ __forceinline__ void stage8(
    const u16* __restrict__ sp, int cst, int c0, int z0, size_t cell,
    int gx, int gy, bool bulk,
    const u16* __restrict__ exb, const u16* __restrict__ eyb,
    const u16* __restrict__ ezb, const u16* __restrict__ rdn,
    const u16* __restrict__ rq2, float* o) {
  const u16* pc0 = sp + (c0 << 7) + z0;
  uint4 pc = *(const uint4*)pc0;
  u16 zmu = (z0 > 0)   ? pc0[-1] : (u16)0;
  u16 zpu = (z0 < 120) ? pc0[8]  : (u16)0;
  uint4 xp = *(const uint4*)(pc0 + (cst << 7));
  uint4 xm = *(const uint4*)(pc0 - (cst << 7));
  uint4 yp = *(const uint4*)(pc0 + 128);
  uint4 ym = *(const uint4*)(pc0 - 128);

  float pz[10];
  pz[0] = bf2f(zmu); up8(pc, pz + 1); pz[9] = bf2f(zpu);
  float xpA[8], xmA[8], ypA[8], ymA[8];
  up8(xp, xpA); up8(xm, xmA); up8(yp, ypA); up8(ym, ymA);

  if (bulk) {
    float rdc  = bf2f(f2bf(__builtin_amdgcn_rcpf(474.0f)));   // 6*79
    float rdc0 = bf2f(f2bf(__builtin_amdgcn_rcpf(395.0f)));   // z=0
#pragma unroll
    for (int i = 0; i < 8; ++i) {
      float s = xpA[i] + xmA[i] + ypA[i] + ymA[i] + pz[i] + pz[i + 2];
      float rd = (z0 + i == 0) ? rdc0 : rdc;
      o[i] = rd * (79.0f * s);
    }
  } else {
    const uint4 z4 = make_uint4(0, 0, 0, 0);
    uint4 ec  = *(const uint4*)(exb + cell);
    uint4 em  = (gx > 0) ? *(const uint4*)(exb + cell - 16384) : z4;
    uint4 yc  = *(const uint4*)(eyb + cell);
    uint4 ym4 = (gy > 0) ? *(const uint4*)(eyb + cell - 128) : z4;
    uint4 zc  = *(const uint4*)(ezb + cell);
    u16 ezm0  = (z0 > 0) ? ezb[cell - 1] : (u16)0;
    uint4 rd4 = *(const uint4*)(rdn + cell);
    uint4 rq4 = *(const uint4*)(rq2 + cell);
    float exA[8], exmA[8], eyA[8], eymA[8], ezA[9], rdA[8], rqA[8];
    up8(ec, exA); up8(em, exmA); up8(yc, eyA); up8(ym4, eymA);
    ezA[0] = bf2f(ezm0); up8(zc, ezA + 1);
    up8(rd4, rdA); up8(rq4, rqA);
#pragma unroll
    for (int i = 0; i < 8; ++i) {
      float num = exA[i] * xpA[i];
      num = fmaf(exmA[i], xmA[i], num);
      num = fmaf(eyA[i],  ypA[i], num);
      num = fmaf(eymA[i], ymA[i], num);
      num = fmaf(ezA[i + 1], pz[i + 2], num);
      num = fmaf(ezA[i],     pz[i],     num);
      o[i] = fmaf(rdA[i], num, rqA[i]);
    }
  }
}

// ---------------------------------------------------------------------------
// Fused double sweep, 8x4 output tile: s0 12x8x128 (24.6 KB) + s1 10x6x128
// (15.4 KB) = ~40 KB LDS -> 4 blocks/CU; grid 1024 = one resident
// generation, so load/compute phases overlap across blocks (the R10 62.6 KB
// tile capped at 2 blocks/CU and was latency-serialized at ~31 us).
// XCD swizzle: flat&7 = XCD, each owns a fixed 16-cell x-slab.
// ---------------------------------------------------------------------------
__global__ __launch_bounds__(256) void fused2_kernel(
    const u16* __restrict__ pin, u16* __restrict__ pout,
    const u16* __restrict__ exb, const u16* __restrict__ eyb,
    const u16* __restrict__ ezb, const u16* __restrict__ rdn,
    const u16* __restrict__ rq2, const unsigned char* __restrict__ pure) {
  __shared__ u16 s0[12 * 8 * 128];
  __shared__ u16 s1[10 * 6 * 128];
  __shared__ unsigned char sbulk[96];

  const int flat = blockIdx.x;
  const int xcd = flat & 7;
  const int idx = flat >> 3;
  const int x0 = ((xcd << 1) | (idx & 1)) * 8;   // 16 x-tiles, 2 per XCD
  const int rem = idx >> 1;
  const int y0 = (rem & 31) * 4;                 // 32 y-tiles
  const int b = rem >> 5;

  const int tid = threadIdx.x;
  const size_t bbase = (size_t)b << 21;
  const uint4 z4 = make_uint4(0, 0, 0, 0);

  // per-column bulk flags for the 12x8 region (self + 4 xy-neighbors pure)
  if (tid < 96) {
    int cx = tid >> 3, cy = tid & 7;
    int gx = x0 - 2 + cx, gy = y0 - 2 + cy;
    bool ok = false;
    if (gx >= 1 && gx <= 126 && gy >= 1 && gy <= 126) {
      const unsigned char* P = pure + ((size_t)b << 14);
      ok = P[(gx << 7) + gy] && P[((gx - 1) << 7) + gy] &&
           P[((gx + 1) << 7) + gy] && P[(gx << 7) + gy - 1] &&
           P[(gx << 7) + gy + 1];
    }
    sbulk[tid] = ok ? 1 : 0;
  }

  // load phi 12x8x128 (out-of-box columns zero-filled)
  for (int i = tid; i < 96 * 16; i += 256) {
    int col = i >> 4, zc = i & 15;
    int cx = col >> 3, cy = col & 7;
    int gx = x0 - 2 + cx, gy = y0 - 2 + cy;
    uint4 vv = z4;
    if ((unsigned)gx < 128u && (unsigned)gy < 128u)
      vv = *(const uint4*)(pin + (bbase | (gx << 14) | (gy << 7) | (zc << 3)));
    ((uint4*)s0)[(col << 4) + zc] = vv;
  }
  __syncthreads();

  // stage 1: sweep k+1 on 10x6 -> s1 (bf16)
  for (int u = tid; u < 60 * 16; u += 256) {
    int col = u >> 4, zc = u & 15, zz = zc << 3;
    int cx = col / 6, cy = col - cx * 6;
    int gx = x0 - 1 + cx, gy = y0 - 1 + cy;
    uint4* dst = (uint4*)(s1 + (col << 7) + zz);
    if ((unsigned)gx >= 128u || (unsigned)gy >= 128u) { *dst = z4; continue; }
    int c0 = (cx + 1) * 8 + (cy + 1);
    size_t cell = bbase | (gx << 14) | (gy << 7) | zz;
    float o[8];
    stage8(s0, 8, c0, zz, cell, gx, gy, sbulk[c0] != 0,
           exb, eyb, ezb, rdn, rq2, o);
    *dst = pk8(o);
  }
  __syncthreads();

  // stage 2: sweep k+2 on 8x4 -> global
  for (int u = tid; u < 32 * 16; u += 256) {
    int col = u >> 4, zc = u & 15, zz = zc << 3;
    int cx = col >> 2, cy = col & 3;
    int gx = x0 + cx, gy = y0 + cy;
    int c1 = (cx + 1) * 6 + (cy + 1);
    size_t cell = bbase | (gx << 14) | (gy << 7) | zz;
    float o[8];
    stage8(s1, 6, c1, zz, cell, gx, gy,
           sbulk[(cx + 2) * 8 + (cy + 2)] != 0, exb, eyb, ezb, rdn, rq2, o);
    *(uint4*)(pout + cell) = pk8(o);
  }
}

// ---------------------------------------------------------------------------
// Single sweep (final): fp32 write to d_out.
// ---------------------------------------------------------------------------
__global__ __launch_bounds__(256) void sweep_final_kernel(
    const u16* __restrict__ pin, float* __restrict__ poutf,
    const u16* __restrict__ exb, const u16* __restrict__ eyb,
    const u16* __restrict__ ezb, const u16* __restrict__ rdn,
    const u16* __restrict__ rq2, const unsigned char* __restrict__ flags,
    int units) {
  int t = blockIdx.x * 256 + threadIdx.x;
  if (t >= units) return;
  int b = t >> 18;
  int r = t & ((1 << 18) - 1);
  int zg = r & 15, y = (r >> 4) & 127, x = r >> 11;
  int z0 = zg << 3;
  int v = (x << 14) | (y << 7) | z0;
  size_t cell = (size_t)b * MCELLS + v;

  const uint4 z4 = make_uint4(0, 0, 0, 0);
  uint4 pc = *(const uint4*)(pin + cell);
  u16 zmu = (z0 > 0)   ? pin[cell - 1] : (u16)0;
  u16 zpu = (z0 < 120) ? pin[cell + 8] : (u16)0;
  uint4 xp = (x < 127) ? *(const uint4*)(pin + cell + 16384) : z4;
  uint4 xm = (x > 0)   ? *(const uint4*)(pin + cell - 16384) : z4;
  uint4 yp = (y < 127) ? *(const uint4*)(pin + cell + 128) : z4;
  uint4 ym = (y > 0)   ? *(const uint4*)(pin + cell - 128) : z4;

  float pz[10];
  pz[0] = bf2f(zmu); up8(pc, pz + 1); pz[9] = bf2f(zpu);
  float xpA[8], xmA[8], ypA[8], ymA[8];
  up8(xp, xpA); up8(xm, xmA); up8(yp, ypA); up8(ym, ymA);

  bool bulk = flags[(b << 12) + (x << 5) + (y >> 2)] != 0;

  float o[8];
  if (bulk) {
    float rdc  = bf2f(f2bf(__builtin_amdgcn_rcpf(474.0f)));
    float rdc0 = bf2f(f2bf(__builtin_amdgcn_rcpf(395.0f)));
#pragma unroll
    for (int i = 0; i < 8; ++i) {
      float s = xpA[i] + xmA[i] + ypA[i] + ymA[i] + pz[i] + pz[i + 2];
      float rd = (z0 + i == 0) ? rdc0 : rdc;
      o[i] = rd * (79.0f * s);
    }
  } else {
    uint4 ec  = *(const uint4*)(exb + cell);
    uint4 em  = (x > 0) ? *(const uint4*)(exb + cell - 16384) : z4;
    uint4 yc  = *(const uint4*)(eyb + cell);
    uint4 ym4 = (y > 0) ? *(const uint4*)(eyb + cell - 128) : z4;
    uint4 zc  = *(const uint4*)(ezb + cell);
    u16 ezm0  = (z0 > 0) ? ezb[cell - 1] : (u16)0;
    uint4 rd4 = *(const uint4*)(rdn + cell);
    uint4 rq4 = *(const uint4*)(rq2 + cell);
    float exA[8], exmA[8], eyA[8], eymA[8], ezA[9], rdA[8], rqA[8];
    up8(ec, exA); up8(em, exmA); up8(yc, eyA); up8(ym4, eymA);
    ezA[0] = bf2f(ezm0); up8(zc, ezA + 1);
    up8(rd4, rdA); up8(rq4, rqA);
#pragma unroll
    for (int i = 0; i < 8; ++i) {
      float num = exA[i] * xpA[i];
      num = fmaf(exmA[i], xmA[i], num);
      num = fmaf(eyA[i],  ypA[i], num);
      num = fmaf(eymA[i], ymA[i], num);
      num = fmaf(ezA[i + 1], pz[i + 2], num);
      num = fmaf(ezA[i],     pz[i],     num);
      o[i] = fmaf(rdA[i], num, rqA[i]);
    }
  }
  *(float4*)(poutf + cell)     = make_float4(o[0], o[1], o[2], o[3]);
  *(float4*)(poutf + cell + 4) = make_float4(o[4], o[5], o[6], o[7]);
}

// ---------------------------------------------------------------------------
// Fallback fp32 Jacobi (tiny ws)
// ---------------------------------------------------------------------------
__global__ __launch_bounds__(256) void jacobi_kernel(
    const float* __restrict__ phi_in, float* __restrict__ phi_out,
    const float* __restrict__ eps, const float* __restrict__ rhs, int B) {
  int i = blockIdx.x * blockDim.x + threadIdx.x;
  if (i >= B * MCELLS) return;
  int b = i >> 21;
  int v = i & (MCELLS - 1);
  int z = v & 127, y = (v >> 7) & 127, x = v >> 14;

  const float* ex = eps + (size_t)(b * 4 + 0) * MCELLS;
  const float* ey = eps + (size_t)(b * 4 + 1) * MCELLS;
  const float* ez = eps + (size_t)(b * 4 + 2) * MCELLS;
  const float* lm = eps + (size_t)(b * 4 + 3) * MCELLS;
  const float* p  = phi_in + (size_t)b * MCELLS;

  float exc = ex[v], eyc = ey[v], ezc = ez[v];
  float exm = (x > 0) ? ex[v - BOX * BOX] : 0.0f;
  float eym = (y > 0) ? ey[v - BOX]       : 0.0f;
  float ezm = (z > 0) ? ez[v - 1]         : 0.0f;

  float num = rhs[i];
  num += (x < BOX - 1) ? exc * p[v + BOX * BOX] : 0.0f;
  num += (x > 0)       ? exm * p[v - BOX * BOX] : 0.0f;
  num += (y < BOX - 1) ? eyc * p[v + BOX]       : 0.0f;
  num += (y > 0)       ? eym * p[v - BOX]       : 0.0f;
  num += (z < BOX - 1) ? ezc * p[v + 1]         : 0.0f;
  num += (z > 0)       ? ezm * p[v - 1]         : 0.0f;

  float den = exc + exm + eyc + eym + ezc + ezm + 0.106f * lm[v];
  phi_out[i] = num / den;
}

// ---------------------------------------------------------------------------
extern "C" void kernel_launch(void* const* d_in, const int* in_sizes, int n_in,
                              void* d_out, int out_size, void* d_ws,
                              size_t ws_size, hipStream_t stream) {
  const float* coords    = (const float*)d_in[0];
  const float* params    = (const float*)d_in[1];
  const int*   num_atoms = (const int*)d_in[2];

  const int B = in_sizes[2];
  const int N = in_sizes[1] / (2 * B);

  float* out = (float*)d_out;
  float* q   = out;                            // (B, M)
  float* eps = out + (size_t)B * MCELLS;       // (B, 4, M)
  float* phi = out + (size_t)B * MCELLS * 5;   // (B, M)

  const size_t BM = (size_t)B * MCELLS;
  u16* phiA = (u16*)d_ws;
  u16* phiB = phiA + BM;
  u16* exb  = phiB + BM;
  u16* eyb  = exb + BM;
  u16* ezb  = eyb + BM;
  u16* rdn  = ezb + BM;
  u16* rq2  = rdn + BM;
  unsigned char* pureb = (unsigned char*)(rq2 + BM);
  unsigned char* flags = pureb + (size_t)B * 16384;
  const size_t need = BM * 14 + (size_t)B * (16384 + 4096);

  const bool fast = (ws_size >= need);

  hipMemsetAsync(q, 0, sizeof(float) * BM, stream);   // scatter accumulator

  eps_gather_kernel<<<dim3(16, 16, 16 * B), 256, 0, stream>>>(
      coords, params, num_atoms, eps, N);
  q_scatter_kernel<<<(B * N + 255) / 256, 256, 0, stream>>>(
      coords, params, num_atoms, q, N, B);

  if (fast) {
    const int pblocks = B * 1024;
    prep8_kernel<<<pblocks, 256, 0, stream>>>(eps, q, exb, eyb, ezb, rdn, rq2,
                                              phiA, pureb, B);
    flag_kernel<<<(B * 4096 + 255) / 256, 256, 0, stream>>>(pureb, flags, B);

    // prep did sweep 1 (phi1 in phiA). 14 fused pairs = sweeps 2..29,
    // ping-pong A->B->A (phi29 ends in A). Final single sweep 30 -> fp32 out.
    u16* pa = phiA;
    u16* pb = phiB;
    for (int k = 0; k < 14; ++k) {
      fused2_kernel<<<512 * B, 256, 0, stream>>>(
          pa, pb, exb, eyb, ezb, rdn, rq2, pureb);
      u16* tmp = pa; pa = pb; pb = tmp;
    }
    const int units = B * (MCELLS / 8);
    sweep_final_kernel<<<(units + 255) / 256, 256, 0, stream>>>(
        pa, phi, exb, eyb, ezb, rdn, rq2, flags, units);
  } else {
    hipMemsetAsync(phi, 0, sizeof(float) * BM, stream);
    float* pa = phi;
    float* pb = (float*)d_ws;
    int total = (int)BM;
    for (int it = 0; it < 30; ++it) {
      jacobi_kernel<<<(total + 255) / 256, 256, 0, stream>>>(pa, pb, eps, q, B);
      float* tmp = pa; pa = pb; pb = tmp;
    }
  }
}